// Round 1
// baseline (2683.530 us; speedup 1.0000x reference)
//
#include <hip/hip_runtime.h>
#include <cstdint>
#include <cstddef>

// ---------------- problem constants ----------------
constexpr int B_   = 2;
constexpr int L_   = 2048;
constexpr int F_   = 128;
constexpr int DM_  = 768;
constexpr int NL_  = 4;
constexpr int DS_  = 16;
constexpr int DC_  = 4;
constexpr int DI_  = 2 * DM_;          // 1536
constexpr int DR_  = (DM_ + 15) / 16;  // 48
constexpr int BL_  = B_ * L_;          // 4096 rows
constexpr int NXZ_ = 2 * DI_;          // 3072
constexpr int DBC_ = DR_ + 2 * DS_;    // 80
constexpr int NCH_ = 32;               // scan chunks
constexpr int TCH_ = L_ / NCH_;        // 64 timesteps per chunk

#define DEV_INLINE __device__ __forceinline__

DEV_INLINE float sigmoidf_(float x) { return 1.f / (1.f + __expf(-x)); }
DEV_INLINE float siluf_(float x)    { return x * sigmoidf_(x); }
DEV_INLINE float softplusf_(float x){ return x > 20.f ? x : log1pf(expf(x)); }

// ---------------- generic tiled f32 GEMM ----------------
// C[M,N] (+)= A[M,K] @ B[K,N]; row-major with explicit leading dims.
// 64x64 tile, BK=16, 256 threads, 4x4 microtile.
// Requires: M % 64 == 0, K % 16 == 0, lda/ldb/ldc % 4 == 0. N arbitrary.
template<bool BIAS, bool SOFTPLUS, bool ACCUM>
__global__ __launch_bounds__(256)
void gemm_f32(const float* __restrict__ A, int lda,
              const float* __restrict__ Bm, int ldb,
              float* __restrict__ C, int ldc,
              const float* __restrict__ bias,
              int M, int N, int K)
{
    __shared__ float As[16][64];
    __shared__ float Bs[16][64];

    const int tid  = threadIdx.x;
    const int col0 = blockIdx.x * 64;
    const int row0 = blockIdx.y * 64;
    const int ty   = tid >> 4;          // 0..15
    const int tx   = tid & 15;          // 0..15

    const int arow = row0 + (tid >> 2); // 0..63 within tile
    const int akk  = (tid & 3) * 4;     // k offset 0,4,8,12
    const int bkk  = tid >> 4;          // 0..15
    const int bcol = col0 + (tid & 15) * 4;

    float acc[4][4] = {};

    for (int k0 = 0; k0 < K; k0 += 16) {
        float4 av = *reinterpret_cast<const float4*>(&A[(size_t)arow * lda + k0 + akk]);
        float4 bv;
        if (bcol + 3 < N) {
            bv = *reinterpret_cast<const float4*>(&Bm[(size_t)(k0 + bkk) * ldb + bcol]);
        } else {
            float t0 = (bcol + 0 < N) ? Bm[(size_t)(k0 + bkk) * ldb + bcol + 0] : 0.f;
            float t1 = (bcol + 1 < N) ? Bm[(size_t)(k0 + bkk) * ldb + bcol + 1] : 0.f;
            float t2 = (bcol + 2 < N) ? Bm[(size_t)(k0 + bkk) * ldb + bcol + 2] : 0.f;
            float t3 = (bcol + 3 < N) ? Bm[(size_t)(k0 + bkk) * ldb + bcol + 3] : 0.f;
            bv = make_float4(t0, t1, t2, t3);
        }
        __syncthreads();
        {
            const int r = tid >> 2;
            As[akk + 0][r] = av.x;
            As[akk + 1][r] = av.y;
            As[akk + 2][r] = av.z;
            As[akk + 3][r] = av.w;
            *reinterpret_cast<float4*>(&Bs[bkk][(tid & 15) * 4]) = bv;
        }
        __syncthreads();

        #pragma unroll
        for (int k = 0; k < 16; ++k) {
            float4 a4 = *reinterpret_cast<const float4*>(&As[k][ty * 4]);
            float4 b4 = *reinterpret_cast<const float4*>(&Bs[k][tx * 4]);
            const float aa[4] = {a4.x, a4.y, a4.z, a4.w};
            const float bb[4] = {b4.x, b4.y, b4.z, b4.w};
            #pragma unroll
            for (int i = 0; i < 4; ++i)
                #pragma unroll
                for (int j = 0; j < 4; ++j)
                    acc[i][j] = fmaf(aa[i], bb[j], acc[i][j]);
        }
    }

    #pragma unroll
    for (int i = 0; i < 4; ++i) {
        const int r = row0 + ty * 4 + i;
        #pragma unroll
        for (int j = 0; j < 4; ++j) {
            const int c = col0 + tx * 4 + j;
            if (c < N) {
                float v = acc[i][j];
                if (BIAS)     v += bias[c];
                if (SOFTPLUS) v = softplusf_(v);
                if (ACCUM)    v += C[(size_t)r * ldc + c];
                C[(size_t)r * ldc + c] = v;
            }
        }
    }
}

// ---------------- row LayerNorm (768 = 3*256) ----------------
__global__ __launch_bounds__(256)
void ln_rows(const float* __restrict__ x, const float* __restrict__ g,
             const float* __restrict__ bb, float* __restrict__ o)
{
    const int r = blockIdx.x;
    const float* xr = x + (size_t)r * DM_;
    const int tid = threadIdx.x;

    float v[3];
    float sum = 0.f, sumsq = 0.f;
    #pragma unroll
    for (int j = 0; j < 3; ++j) {
        v[j] = xr[tid + j * 256];
        sum   += v[j];
        sumsq += v[j] * v[j];
    }
    #pragma unroll
    for (int off = 32; off > 0; off >>= 1) {
        sum   += __shfl_xor(sum, off);
        sumsq += __shfl_xor(sumsq, off);
    }
    __shared__ float ws[2][4];
    const int lane = tid & 63, wid = tid >> 6;
    if (lane == 0) { ws[0][wid] = sum; ws[1][wid] = sumsq; }
    __syncthreads();
    const float ts  = ws[0][0] + ws[0][1] + ws[0][2] + ws[0][3];
    const float tsq = ws[1][0] + ws[1][1] + ws[1][2] + ws[1][3];
    const float m   = ts / DM_;
    const float var = tsq / DM_ - m * m;
    const float rs  = rsqrtf(var + 1e-5f);
    float* orow = o + (size_t)r * DM_;
    #pragma unroll
    for (int j = 0; j < 3; ++j) {
        const int c = tid + j * 256;
        orow[c] = (v[j] - m) * rs * g[c] + bb[c];
    }
}

// ---------------- depthwise causal conv (DC=4) + SiLU ----------------
__global__ __launch_bounds__(256)
void conv_silu(const float* __restrict__ xz, const float* __restrict__ cw,
               const float* __restrict__ cb, float* __restrict__ u)
{
    const int t0 = blockIdx.x * 256 + threadIdx.x;   // over BL_*DI_
    const int d = t0 % DI_;
    const int r = t0 / DI_;
    const int b = r / L_, l = r % L_;

    const float w0 = cw[d * DC_ + 0], w1 = cw[d * DC_ + 1];
    const float w2 = cw[d * DC_ + 2], w3 = cw[d * DC_ + 3];
    float acc = cb[d];
    const size_t base = (size_t)(b * L_) * NXZ_ + d;
    if (l - 3 >= 0) acc = fmaf(xz[base + (size_t)(l - 3) * NXZ_], w0, acc);
    if (l - 2 >= 0) acc = fmaf(xz[base + (size_t)(l - 2) * NXZ_], w1, acc);
    if (l - 1 >= 0) acc = fmaf(xz[base + (size_t)(l - 1) * NXZ_], w2, acc);
    acc = fmaf(xz[base + (size_t)l * NXZ_], w3, acc);
    u[(size_t)r * DI_ + d] = siluf_(acc);
}

// ---------------- chunked selective scan ----------------
// pass A: per (b, chunk, d): local scan from s=0, store end state + sum(delta)
__global__ __launch_bounds__(256)
void scan_passA(const float* __restrict__ delta, const float* __restrict__ u,
                const float* __restrict__ dbc, const float* __restrict__ A_log,
                float* __restrict__ cs, float* __restrict__ csum)
{
    const int t0 = blockIdx.x * 256 + threadIdx.x;   // over B_*NCH_*DI_
    const int d = t0 % DI_;
    const int c = (t0 / DI_) % NCH_;
    const int b = t0 / (DI_ * NCH_);

    float Ar[DS_];
    #pragma unroll
    for (int n = 0; n < DS_; ++n) Ar[n] = -expf(A_log[d * DS_ + n]);

    float s[DS_];
    #pragma unroll
    for (int n = 0; n < DS_; ++n) s[n] = 0.f;
    float sumd = 0.f;

    const int rowbase = b * L_ + c * TCH_;
    for (int t = 0; t < TCH_; ++t) {
        const int row = rowbase + t;
        const float dv = delta[(size_t)row * DI_ + d];
        const float uv = u[(size_t)row * DI_ + d];
        const float du = dv * uv;
        sumd += dv;
        float Bv[DS_];
        const float4* Bp = reinterpret_cast<const float4*>(&dbc[(size_t)row * DBC_ + DR_]);
        *reinterpret_cast<float4*>(&Bv[0])  = Bp[0];
        *reinterpret_cast<float4*>(&Bv[4])  = Bp[1];
        *reinterpret_cast<float4*>(&Bv[8])  = Bp[2];
        *reinterpret_cast<float4*>(&Bv[12]) = Bp[3];
        #pragma unroll
        for (int n = 0; n < DS_; ++n)
            s[n] = fmaf(s[n], __expf(dv * Ar[n]), du * Bv[n]);
    }
    const size_t cbase = ((size_t)(b * NCH_ + c) * DS_) * DI_ + d;
    #pragma unroll
    for (int n = 0; n < DS_; ++n) cs[cbase + (size_t)n * DI_] = s[n];
    csum[(size_t)(b * NCH_ + c) * DI_ + d] = sumd;
}

// pass B: sequential combine over chunks; cs becomes the chunk INITIAL state
__global__ __launch_bounds__(256)
void scan_passB(float* __restrict__ cs, const float* __restrict__ csum,
                const float* __restrict__ A_log)
{
    const int t0 = blockIdx.x * 256 + threadIdx.x;   // over B_*DS_*DI_
    const int d = t0 % DI_;
    const int n = (t0 / DI_) % DS_;
    const int b = t0 / (DI_ * DS_);
    const float An = -expf(A_log[d * DS_ + n]);

    float carry = 0.f;
    for (int c = 0; c < NCH_; ++c) {
        const size_t idx = ((size_t)(b * NCH_ + c) * DS_ + n) * DI_ + d;
        const float loc = cs[idx];
        cs[idx] = carry;
        carry = fmaf(carry, __expf(An * csum[(size_t)(b * NCH_ + c) * DI_ + d]), loc);
    }
}

// pass C: replay with correct initial state; fuse +u*Dv and *silu(z); write y
__global__ __launch_bounds__(256)
void scan_passC(const float* __restrict__ delta, const float* __restrict__ u,
                const float* __restrict__ dbc, const float* __restrict__ A_log,
                const float* __restrict__ cs, const float* __restrict__ Dvp,
                const float* __restrict__ xz, float* __restrict__ y)
{
    const int t0 = blockIdx.x * 256 + threadIdx.x;   // over B_*NCH_*DI_
    const int d = t0 % DI_;
    const int c = (t0 / DI_) % NCH_;
    const int b = t0 / (DI_ * NCH_);

    float Ar[DS_];
    #pragma unroll
    for (int n = 0; n < DS_; ++n) Ar[n] = -expf(A_log[d * DS_ + n]);

    float s[DS_];
    const size_t cbase = ((size_t)(b * NCH_ + c) * DS_) * DI_ + d;
    #pragma unroll
    for (int n = 0; n < DS_; ++n) s[n] = cs[cbase + (size_t)n * DI_];

    const float Dvd = Dvp[d];
    const int rowbase = b * L_ + c * TCH_;
    for (int t = 0; t < TCH_; ++t) {
        const int row = rowbase + t;
        const float dv = delta[(size_t)row * DI_ + d];
        const float uv = u[(size_t)row * DI_ + d];
        const float du = dv * uv;
        float Bv[DS_], Cv[DS_];
        const float4* Bp = reinterpret_cast<const float4*>(&dbc[(size_t)row * DBC_ + DR_]);
        *reinterpret_cast<float4*>(&Bv[0])  = Bp[0];
        *reinterpret_cast<float4*>(&Bv[4])  = Bp[1];
        *reinterpret_cast<float4*>(&Bv[8])  = Bp[2];
        *reinterpret_cast<float4*>(&Bv[12]) = Bp[3];
        const float4* Cp = reinterpret_cast<const float4*>(&dbc[(size_t)row * DBC_ + DR_ + DS_]);
        *reinterpret_cast<float4*>(&Cv[0])  = Cp[0];
        *reinterpret_cast<float4*>(&Cv[4])  = Cp[1];
        *reinterpret_cast<float4*>(&Cv[8])  = Cp[2];
        *reinterpret_cast<float4*>(&Cv[12]) = Cp[3];

        float yv = 0.f;
        #pragma unroll
        for (int n = 0; n < DS_; ++n) {
            s[n] = fmaf(s[n], __expf(dv * Ar[n]), du * Bv[n]);
            yv = fmaf(s[n], Cv[n], yv);
        }
        yv = fmaf(uv, Dvd, yv);
        const float zv = xz[(size_t)row * NXZ_ + DI_ + d];
        yv *= siluf_(zv);
        y[(size_t)row * DI_ + d] = yv;
    }
}

// ---------------- host launch ----------------
extern "C" void kernel_launch(void* const* d_in, const int* in_sizes, int n_in,
                              void* d_out, int out_size, void* d_ws, size_t ws_size,
                              hipStream_t stream)
{
    const float* x      = (const float*)d_in[0];
    const float* Wi     = (const float*)d_in[1];
    const float* bi     = (const float*)d_in[2];
    const float* ln_g   = (const float*)d_in[3];
    const float* ln_b   = (const float*)d_in[4];
    const float* in_w   = (const float*)d_in[5];
    const float* conv_w = (const float*)d_in[6];
    const float* conv_b = (const float*)d_in[7];
    const float* xproj  = (const float*)d_in[8];
    const float* dt_w   = (const float*)d_in[9];
    const float* dt_b   = (const float*)d_in[10];
    const float* A_log  = (const float*)d_in[11];
    const float* Dvp    = (const float*)d_in[12];
    const float* out_w  = (const float*)d_in[13];
    const float* fn_g   = (const float*)d_in[14];
    const float* fn_b   = (const float*)d_in[15];
    float* out = (float*)d_out;

    float* ws = (float*)d_ws;
    size_t off = 0;
    auto alloc = [&](size_t n) { float* p = ws + off; off += n; return p; };
    float* h     = alloc((size_t)BL_ * DM_);
    float* hn    = alloc((size_t)BL_ * DM_);
    float* xz    = alloc((size_t)BL_ * NXZ_);
    float* u     = alloc((size_t)BL_ * DI_);
    float* dbc   = alloc((size_t)BL_ * DBC_);
    float* delta = alloc((size_t)BL_ * DI_);
    float* y     = alloc((size_t)BL_ * DI_);
    float* cs    = alloc((size_t)B_ * NCH_ * DS_ * DI_);
    float* csum  = alloc((size_t)B_ * NCH_ * DI_);

    const dim3 blk(256);

    // h = x @ Wi + bi
    gemm_f32<true, false, false><<<dim3(DM_ / 64, BL_ / 64), blk, 0, stream>>>(
        x, F_, Wi, DM_, h, DM_, bi, BL_, DM_, F_);

    for (int i = 0; i < NL_; ++i) {
        ln_rows<<<BL_, blk, 0, stream>>>(h, ln_g + i * DM_, ln_b + i * DM_, hn);

        gemm_f32<false, false, false><<<dim3(NXZ_ / 64, BL_ / 64), blk, 0, stream>>>(
            hn, DM_, in_w + (size_t)i * DM_ * NXZ_, NXZ_, xz, NXZ_, nullptr, BL_, NXZ_, DM_);

        conv_silu<<<(BL_ * DI_) / 256, blk, 0, stream>>>(
            xz, conv_w + (size_t)i * DI_ * DC_, conv_b + (size_t)i * DI_, u);

        gemm_f32<false, false, false><<<dim3((DBC_ + 63) / 64, BL_ / 64), blk, 0, stream>>>(
            u, DI_, xproj + (size_t)i * DI_ * DBC_, DBC_, dbc, DBC_, nullptr, BL_, DBC_, DI_);

        gemm_f32<true, true, false><<<dim3(DI_ / 64, BL_ / 64), blk, 0, stream>>>(
            dbc, DBC_, dt_w + (size_t)i * DR_ * DI_, DI_, delta, DI_, dt_b + (size_t)i * DI_,
            BL_, DI_, DR_);

        scan_passA<<<(B_ * NCH_ * DI_) / 256, blk, 0, stream>>>(
            delta, u, dbc, A_log + (size_t)i * DI_ * DS_, cs, csum);
        scan_passB<<<(B_ * DS_ * DI_) / 256, blk, 0, stream>>>(
            cs, csum, A_log + (size_t)i * DI_ * DS_);
        scan_passC<<<(B_ * NCH_ * DI_) / 256, blk, 0, stream>>>(
            delta, u, dbc, A_log + (size_t)i * DI_ * DS_, cs, Dvp + (size_t)i * DI_, xz, y);

        gemm_f32<false, false, true><<<dim3(DM_ / 64, BL_ / 64), blk, 0, stream>>>(
            y, DI_, out_w + (size_t)i * DI_ * DM_, DM_, h, DM_, nullptr, BL_, DM_, DI_);
    }

    ln_rows<<<BL_, blk, 0, stream>>>(h, fn_g, fn_b, out);
}

// Round 2
// 1201.267 us; speedup vs baseline: 2.2339x; 2.2339x over previous
//
#include <hip/hip_runtime.h>
#include <hip/hip_bf16.h>
#include <cstdint>
#include <cstddef>

// ---------------- problem constants ----------------
constexpr int B_   = 2;
constexpr int L_   = 2048;
constexpr int F_   = 128;
constexpr int DM_  = 768;
constexpr int NL_  = 4;
constexpr int DS_  = 16;
constexpr int DC_  = 4;
constexpr int DI_  = 2 * DM_;          // 1536
constexpr int DR_  = (DM_ + 15) / 16;  // 48
constexpr int BL_  = B_ * L_;          // 4096 rows
constexpr int NXZ_ = 2 * DI_;          // 3072
constexpr int DBC_ = DR_ + 2 * DS_;    // 80
constexpr int NCH_ = 32;               // scan chunks
constexpr int TCH_ = L_ / NCH_;        // 64 timesteps per chunk

#define DEV_INLINE __device__ __forceinline__

typedef __attribute__((ext_vector_type(8))) short  bf16x8;
typedef __attribute__((ext_vector_type(4))) float  f32x4;

DEV_INLINE float sigmoidf_(float x) { return 1.f / (1.f + __expf(-x)); }
DEV_INLINE float siluf_(float x)    { return x * sigmoidf_(x); }
DEV_INLINE float softplusf_(float x){ return x > 20.f ? x : log1pf(expf(x)); }

DEV_INLINE void gload_lds16(const void* g, void* l) {
    __builtin_amdgcn_global_load_lds(
        (const __attribute__((address_space(1))) void*)g,
        (__attribute__((address_space(3))) void*)l, 16, 0, 0);
}

// ---------------- bf16 MFMA GEMM (m97 structure) ----------------
// C[M,N] (+)= A[M,K] @ Bt[N,K]^T.  A,Bt bf16 row-major; C f32.
// 128x128 tile, BK=32, 256 threads = 4 waves, each wave one 64x64 quadrant
// (4x4 frags of 16x16x32).  M%128==0, gridDim.x*128 == padded N, K%32==0.
template<bool BIAS, bool ACCUM, bool NMASK>
__global__ __launch_bounds__(256)
void gemm_mfma(const __hip_bfloat16* __restrict__ A,
               const __hip_bfloat16* __restrict__ Bt,
               float* __restrict__ C, int ldc,
               const float* __restrict__ bias,
               int K, int Nreal)
{
    __shared__ __hip_bfloat16 As[128 * 32];
    __shared__ __hip_bfloat16 Bs[128 * 32];

    const int tid  = threadIdx.x;
    const int lane = tid & 63;
    const int wv   = tid >> 6;
    const int wr   = wv >> 1;           // 0..1
    const int wc   = wv & 1;            // 0..1
    const int row0 = blockIdx.y * 128;
    const int col0 = blockIdx.x * 128;

    // staging: chunk j (j=0,1) covers LDS bytes j*4096 + tid*16
    const int offb = tid * 16;
    const int srow = offb >> 6;          // 0..63
    const int skk  = (offb & 63) >> 1;   // 0,8,16,24
    const size_t ga0 = (size_t)(row0 + srow)      * K + skk;
    const size_t ga1 = (size_t)(row0 + 64 + srow) * K + skk;
    const size_t gb0 = (size_t)(col0 + srow)      * K + skk;
    const size_t gb1 = (size_t)(col0 + 64 + srow) * K + skk;

    const int fr = lane & 15, fq = lane >> 4;

    f32x4 acc[4][4] = {};

    for (int k0 = 0; k0 < K; k0 += 32) {
        gload_lds16(A  + ga0 + k0, &As[tid * 8]);
        gload_lds16(A  + ga1 + k0, &As[tid * 8 + 2048]);
        gload_lds16(Bt + gb0 + k0, &Bs[tid * 8]);
        gload_lds16(Bt + gb1 + k0, &Bs[tid * 8 + 2048]);
        __syncthreads();   // drains vmcnt before any ds_read

        bf16x8 af[4], bfv[4];
        #pragma unroll
        for (int m = 0; m < 4; ++m)
            af[m] = *(const bf16x8*)&As[(wr * 64 + m * 16 + fr) * 32 + fq * 8];
        #pragma unroll
        for (int n = 0; n < 4; ++n)
            bfv[n] = *(const bf16x8*)&Bs[(wc * 64 + n * 16 + fr) * 32 + fq * 8];

        #pragma unroll
        for (int m = 0; m < 4; ++m)
            #pragma unroll
            for (int n = 0; n < 4; ++n)
                acc[m][n] = __builtin_amdgcn_mfma_f32_16x16x32_bf16(
                    af[m], bfv[n], acc[m][n], 0, 0, 0);
        __syncthreads();   // all frag reads done before restage
    }

    // epilogue: C/D layout col=lane&15, row=(lane>>4)*4+reg  [m89-verified]
    #pragma unroll
    for (int m = 0; m < 4; ++m) {
        #pragma unroll
        for (int n = 0; n < 4; ++n) {
            const int col = col0 + wc * 64 + n * 16 + fr;
            if (NMASK && col >= Nreal) continue;
            #pragma unroll
            for (int r = 0; r < 4; ++r) {
                const int row = row0 + wr * 64 + m * 16 + fq * 4 + r;
                float v = acc[m][n][r];
                if (BIAS)  v += bias[col];
                if (ACCUM) v += C[(size_t)row * ldc + col];
                C[(size_t)row * ldc + col] = v;
            }
        }
    }
}

// ---------------- f32 [K][N] -> bf16 [Npad][K] transpose ----------------
// grid: (Npad/32, K/32), block (32,8).  Rows n>=N are written as 0.
__global__ __launch_bounds__(256)
void transpose_f32_bf16(const float* __restrict__ in, __hip_bfloat16* __restrict__ out,
                        int K, int N)
{
    __shared__ float t[32][33];
    const int n0 = blockIdx.x * 32, k0 = blockIdx.y * 32;
    const int tx = threadIdx.x, ty = threadIdx.y;
    #pragma unroll
    for (int r = 0; r < 4; ++r) {
        const int k = k0 + ty + r * 8;
        const int n = n0 + tx;
        t[ty + r * 8][tx] = (n < N) ? in[(size_t)k * N + n] : 0.f;
    }
    __syncthreads();
    #pragma unroll
    for (int r = 0; r < 4; ++r) {
        const int n = n0 + ty + r * 8;
        const int k = k0 + tx;
        out[(size_t)n * K + k] = __float2bfloat16(t[tx][ty + r * 8]);
    }
}

__global__ __launch_bounds__(256)
void cvt_bf16(const float* __restrict__ in, __hip_bfloat16* __restrict__ out, int n)
{
    const int i = blockIdx.x * 256 + threadIdx.x;
    if (i < n) out[i] = __float2bfloat16(in[i]);
}

// ---------------- generic tiled f32 GEMM (dt only now) ----------------
template<bool BIAS, bool SOFTPLUS, bool ACCUM>
__global__ __launch_bounds__(256)
void gemm_f32(const float* __restrict__ A, int lda,
              const float* __restrict__ Bm, int ldb,
              float* __restrict__ C, int ldc,
              const float* __restrict__ bias,
              int M, int N, int K)
{
    __shared__ float As[16][64];
    __shared__ float Bs[16][64];

    const int tid  = threadIdx.x;
    const int col0 = blockIdx.x * 64;
    const int row0 = blockIdx.y * 64;
    const int ty   = tid >> 4;
    const int tx   = tid & 15;

    const int arow = row0 + (tid >> 2);
    const int akk  = (tid & 3) * 4;
    const int bkk  = tid >> 4;
    const int bcol = col0 + (tid & 15) * 4;

    float acc[4][4] = {};

    for (int k0 = 0; k0 < K; k0 += 16) {
        float4 av = *reinterpret_cast<const float4*>(&A[(size_t)arow * lda + k0 + akk]);
        float4 bv;
        if (bcol + 3 < N) {
            bv = *reinterpret_cast<const float4*>(&Bm[(size_t)(k0 + bkk) * ldb + bcol]);
        } else {
            float t0 = (bcol + 0 < N) ? Bm[(size_t)(k0 + bkk) * ldb + bcol + 0] : 0.f;
            float t1 = (bcol + 1 < N) ? Bm[(size_t)(k0 + bkk) * ldb + bcol + 1] : 0.f;
            float t2 = (bcol + 2 < N) ? Bm[(size_t)(k0 + bkk) * ldb + bcol + 2] : 0.f;
            float t3 = (bcol + 3 < N) ? Bm[(size_t)(k0 + bkk) * ldb + bcol + 3] : 0.f;
            bv = make_float4(t0, t1, t2, t3);
        }
        __syncthreads();
        {
            const int r = tid >> 2;
            As[akk + 0][r] = av.x;
            As[akk + 1][r] = av.y;
            As[akk + 2][r] = av.z;
            As[akk + 3][r] = av.w;
            *reinterpret_cast<float4*>(&Bs[bkk][(tid & 15) * 4]) = bv;
        }
        __syncthreads();

        #pragma unroll
        for (int k = 0; k < 16; ++k) {
            float4 a4 = *reinterpret_cast<const float4*>(&As[k][ty * 4]);
            float4 b4 = *reinterpret_cast<const float4*>(&Bs[k][tx * 4]);
            const float aa[4] = {a4.x, a4.y, a4.z, a4.w};
            const float bb[4] = {b4.x, b4.y, b4.z, b4.w};
            #pragma unroll
            for (int i = 0; i < 4; ++i)
                #pragma unroll
                for (int j = 0; j < 4; ++j)
                    acc[i][j] = fmaf(aa[i], bb[j], acc[i][j]);
        }
    }

    #pragma unroll
    for (int i = 0; i < 4; ++i) {
        const int r = row0 + ty * 4 + i;
        #pragma unroll
        for (int j = 0; j < 4; ++j) {
            const int c = col0 + tx * 4 + j;
            if (c < N) {
                float v = acc[i][j];
                if (BIAS)     v += bias[c];
                if (SOFTPLUS) v = softplusf_(v);
                if (ACCUM)    v += C[(size_t)r * ldc + c];
                C[(size_t)r * ldc + c] = v;
            }
        }
    }
}

// ---------------- row LayerNorm (768 = 3*256) ----------------
template<typename OT>
__global__ __launch_bounds__(256)
void ln_rows(const float* __restrict__ x, const float* __restrict__ g,
             const float* __restrict__ bb, OT* __restrict__ o)
{
    const int r = blockIdx.x;
    const float* xr = x + (size_t)r * DM_;
    const int tid = threadIdx.x;

    float v[3];
    float sum = 0.f, sumsq = 0.f;
    #pragma unroll
    for (int j = 0; j < 3; ++j) {
        v[j] = xr[tid + j * 256];
        sum   += v[j];
        sumsq += v[j] * v[j];
    }
    #pragma unroll
    for (int off = 32; off > 0; off >>= 1) {
        sum   += __shfl_xor(sum, off);
        sumsq += __shfl_xor(sumsq, off);
    }
    __shared__ float ws[2][4];
    const int lane = tid & 63, wid = tid >> 6;
    if (lane == 0) { ws[0][wid] = sum; ws[1][wid] = sumsq; }
    __syncthreads();
    const float ts  = ws[0][0] + ws[0][1] + ws[0][2] + ws[0][3];
    const float tsq = ws[1][0] + ws[1][1] + ws[1][2] + ws[1][3];
    const float m   = ts / DM_;
    const float var = tsq / DM_ - m * m;
    const float rs  = rsqrtf(var + 1e-5f);
    OT* orow = o + (size_t)r * DM_;
    #pragma unroll
    for (int j = 0; j < 3; ++j) {
        const int c = tid + j * 256;
        orow[c] = OT((v[j] - m) * rs * g[c] + bb[c]);
    }
}

// ---------------- depthwise causal conv (DC=4) + SiLU -> bf16 ----------------
__global__ __launch_bounds__(256)
void conv_silu(const float* __restrict__ xz, const float* __restrict__ cw,
               const float* __restrict__ cb, __hip_bfloat16* __restrict__ u)
{
    const int t0 = blockIdx.x * 256 + threadIdx.x;
    const int d = t0 % DI_;
    const int r = t0 / DI_;
    const int b = r / L_, l = r % L_;

    const float w0 = cw[d * DC_ + 0], w1 = cw[d * DC_ + 1];
    const float w2 = cw[d * DC_ + 2], w3 = cw[d * DC_ + 3];
    float acc = cb[d];
    const size_t base = (size_t)(b * L_) * NXZ_ + d;
    if (l - 3 >= 0) acc = fmaf(xz[base + (size_t)(l - 3) * NXZ_], w0, acc);
    if (l - 2 >= 0) acc = fmaf(xz[base + (size_t)(l - 2) * NXZ_], w1, acc);
    if (l - 1 >= 0) acc = fmaf(xz[base + (size_t)(l - 1) * NXZ_], w2, acc);
    acc = fmaf(xz[base + (size_t)l * NXZ_], w3, acc);
    u[(size_t)r * DI_ + d] = __float2bfloat16(siluf_(acc));
}

// ---------------- chunked selective scan ----------------
__global__ __launch_bounds__(256)
void scan_passA(const float* __restrict__ delta, const __hip_bfloat16* __restrict__ u,
                const float* __restrict__ dbc, const float* __restrict__ A_log,
                float* __restrict__ cs, float* __restrict__ csum)
{
    const int t0 = blockIdx.x * 256 + threadIdx.x;
    const int d = t0 % DI_;
    const int c = (t0 / DI_) % NCH_;
    const int b = t0 / (DI_ * NCH_);

    float Ar[DS_];
    #pragma unroll
    for (int n = 0; n < DS_; ++n) Ar[n] = -expf(A_log[d * DS_ + n]);

    float s[DS_];
    #pragma unroll
    for (int n = 0; n < DS_; ++n) s[n] = 0.f;
    float sumd = 0.f;

    const int rowbase = b * L_ + c * TCH_;
    for (int t = 0; t < TCH_; ++t) {
        const int row = rowbase + t;
        const float dv = delta[(size_t)row * DI_ + d];
        const float uv = __bfloat162float(u[(size_t)row * DI_ + d]);
        const float du = dv * uv;
        sumd += dv;
        float Bv[DS_];
        const float4* Bp = reinterpret_cast<const float4*>(&dbc[(size_t)row * DBC_ + DR_]);
        *reinterpret_cast<float4*>(&Bv[0])  = Bp[0];
        *reinterpret_cast<float4*>(&Bv[4])  = Bp[1];
        *reinterpret_cast<float4*>(&Bv[8])  = Bp[2];
        *reinterpret_cast<float4*>(&Bv[12]) = Bp[3];
        #pragma unroll
        for (int n = 0; n < DS_; ++n)
            s[n] = fmaf(s[n], __expf(dv * Ar[n]), du * Bv[n]);
    }
    const size_t cbase = ((size_t)(b * NCH_ + c) * DS_) * DI_ + d;
    #pragma unroll
    for (int n = 0; n < DS_; ++n) cs[cbase + (size_t)n * DI_] = s[n];
    csum[(size_t)(b * NCH_ + c) * DI_ + d] = sumd;
}

__global__ __launch_bounds__(256)
void scan_passB(float* __restrict__ cs, const float* __restrict__ csum,
                const float* __restrict__ A_log)
{
    const int t0 = blockIdx.x * 256 + threadIdx.x;
    const int d = t0 % DI_;
    const int n = (t0 / DI_) % DS_;
    const int b = t0 / (DI_ * DS_);
    const float An = -expf(A_log[d * DS_ + n]);

    float carry = 0.f;
    for (int c = 0; c < NCH_; ++c) {
        const size_t idx = ((size_t)(b * NCH_ + c) * DS_ + n) * DI_ + d;
        const float loc = cs[idx];
        cs[idx] = carry;
        carry = fmaf(carry, __expf(An * csum[(size_t)(b * NCH_ + c) * DI_ + d]), loc);
    }
}

__global__ __launch_bounds__(256)
void scan_passC(const float* __restrict__ delta, const __hip_bfloat16* __restrict__ u,
                const float* __restrict__ dbc, const float* __restrict__ A_log,
                const float* __restrict__ cs, const float* __restrict__ Dvp,
                const float* __restrict__ xz, __hip_bfloat16* __restrict__ y)
{
    const int t0 = blockIdx.x * 256 + threadIdx.x;
    const int d = t0 % DI_;
    const int c = (t0 / DI_) % NCH_;
    const int b = t0 / (DI_ * NCH_);

    float Ar[DS_];
    #pragma unroll
    for (int n = 0; n < DS_; ++n) Ar[n] = -expf(A_log[d * DS_ + n]);

    float s[DS_];
    const size_t cbase = ((size_t)(b * NCH_ + c) * DS_) * DI_ + d;
    #pragma unroll
    for (int n = 0; n < DS_; ++n) s[n] = cs[cbase + (size_t)n * DI_];

    const float Dvd = Dvp[d];
    const int rowbase = b * L_ + c * TCH_;
    for (int t = 0; t < TCH_; ++t) {
        const int row = rowbase + t;
        const float dv = delta[(size_t)row * DI_ + d];
        const float uv = __bfloat162float(u[(size_t)row * DI_ + d]);
        const float du = dv * uv;
        float Bv[DS_], Cv[DS_];
        const float4* Bp = reinterpret_cast<const float4*>(&dbc[(size_t)row * DBC_ + DR_]);
        *reinterpret_cast<float4*>(&Bv[0])  = Bp[0];
        *reinterpret_cast<float4*>(&Bv[4])  = Bp[1];
        *reinterpret_cast<float4*>(&Bv[8])  = Bp[2];
        *reinterpret_cast<float4*>(&Bv[12]) = Bp[3];
        const float4* Cp = reinterpret_cast<const float4*>(&dbc[(size_t)row * DBC_ + DR_ + DS_]);
        *reinterpret_cast<float4*>(&Cv[0])  = Cp[0];
        *reinterpret_cast<float4*>(&Cv[4])  = Cp[1];
        *reinterpret_cast<float4*>(&Cv[8])  = Cp[2];
        *reinterpret_cast<float4*>(&Cv[12]) = Cp[3];

        float yv = 0.f;
        #pragma unroll
        for (int n = 0; n < DS_; ++n) {
            s[n] = fmaf(s[n], __expf(dv * Ar[n]), du * Bv[n]);
            yv = fmaf(s[n], Cv[n], yv);
        }
        yv = fmaf(uv, Dvd, yv);
        const float zv = xz[(size_t)row * NXZ_ + DI_ + d];
        yv *= siluf_(zv);
        y[(size_t)row * DI_ + d] = __float2bfloat16(yv);
    }
}

// ---------------- host launch ----------------
extern "C" void kernel_launch(void* const* d_in, const int* in_sizes, int n_in,
                              void* d_out, int out_size, void* d_ws, size_t ws_size,
                              hipStream_t stream)
{
    const float* x      = (const float*)d_in[0];
    const float* Wi     = (const float*)d_in[1];
    const float* bi     = (const float*)d_in[2];
    const float* ln_g   = (const float*)d_in[3];
    const float* ln_b   = (const float*)d_in[4];
    const float* in_w   = (const float*)d_in[5];
    const float* conv_w = (const float*)d_in[6];
    const float* conv_b = (const float*)d_in[7];
    const float* xproj  = (const float*)d_in[8];
    const float* dt_w   = (const float*)d_in[9];
    const float* dt_b   = (const float*)d_in[10];
    const float* A_log  = (const float*)d_in[11];
    const float* Dvp    = (const float*)d_in[12];
    const float* out_w  = (const float*)d_in[13];
    const float* fn_g   = (const float*)d_in[14];
    const float* fn_b   = (const float*)d_in[15];
    float* out = (float*)d_out;

    float* ws = (float*)d_ws;
    size_t off = 0;
    auto alloc = [&](size_t nfloats) { float* p = ws + off; off += nfloats; return p; };

    // f32 buffers
    float* h     = alloc((size_t)BL_ * DM_);
    float* xz    = alloc((size_t)BL_ * NXZ_);
    float* dbc   = alloc((size_t)BL_ * DBC_);
    float* delta = alloc((size_t)BL_ * DI_);
    float* cs    = alloc((size_t)B_ * NCH_ * DS_ * DI_);
    float* csum  = alloc((size_t)B_ * NCH_ * DI_);
    // bf16 buffers (alloc counts in float units = elems/2)
    __hip_bfloat16* hn_bf = (__hip_bfloat16*)alloc((size_t)BL_ * DM_ / 2);
    __hip_bfloat16* u_bf  = (__hip_bfloat16*)alloc((size_t)BL_ * DI_ / 2);
    __hip_bfloat16* y_bf  = (__hip_bfloat16*)alloc((size_t)BL_ * DI_ / 2);
    __hip_bfloat16* inT   = (__hip_bfloat16*)alloc((size_t)NXZ_ * DM_ / 2);
    __hip_bfloat16* outT  = (__hip_bfloat16*)alloc((size_t)DM_ * DI_ / 2);
    __hip_bfloat16* xprT  = (__hip_bfloat16*)alloc((size_t)128 * DI_ / 2);
    // x_bf aliases y_bf (used only before layer 0), WiT aliases u_bf.
    __hip_bfloat16* x_bf = y_bf;
    __hip_bfloat16* WiT  = u_bf;

    const dim3 blk(256);
    const dim3 tblk(32, 8);

    // input projection: h = x @ Wi + bi   (bf16 MFMA)
    cvt_bf16<<<(BL_ * F_ + 255) / 256, blk, 0, stream>>>(x, x_bf, BL_ * F_);
    transpose_f32_bf16<<<dim3(DM_ / 32, F_ / 32), tblk, 0, stream>>>(Wi, WiT, F_, DM_);
    gemm_mfma<true, false, false><<<dim3(DM_ / 128, BL_ / 128), blk, 0, stream>>>(
        x_bf, WiT, h, DM_, bi, F_, DM_);

    for (int i = 0; i < NL_; ++i) {
        // weight transpose+convert for this layer
        transpose_f32_bf16<<<dim3(NXZ_ / 32, DM_ / 32), tblk, 0, stream>>>(
            in_w + (size_t)i * DM_ * NXZ_, inT, DM_, NXZ_);
        transpose_f32_bf16<<<dim3(DM_ / 32, DI_ / 32), tblk, 0, stream>>>(
            out_w + (size_t)i * DI_ * DM_, outT, DI_, DM_);
        transpose_f32_bf16<<<dim3(128 / 32, DI_ / 32), tblk, 0, stream>>>(
            xproj + (size_t)i * DI_ * DBC_, xprT, DI_, DBC_);

        ln_rows<__hip_bfloat16><<<BL_, blk, 0, stream>>>(
            h, ln_g + i * DM_, ln_b + i * DM_, hn_bf);

        gemm_mfma<false, false, false><<<dim3(NXZ_ / 128, BL_ / 128), blk, 0, stream>>>(
            hn_bf, inT, xz, NXZ_, nullptr, DM_, NXZ_);

        conv_silu<<<(BL_ * DI_) / 256, blk, 0, stream>>>(
            xz, conv_w + (size_t)i * DI_ * DC_, conv_b + (size_t)i * DI_, u_bf);

        gemm_mfma<false, false, true><<<dim3(1, BL_ / 128), blk, 0, stream>>>(
            u_bf, xprT, dbc, DBC_, nullptr, DI_, DBC_);

        gemm_f32<true, true, false><<<dim3(DI_ / 64, BL_ / 64), blk, 0, stream>>>(
            dbc, DBC_, dt_w + (size_t)i * DR_ * DI_, DI_, delta, DI_, dt_b + (size_t)i * DI_,
            BL_, DI_, DR_);

        scan_passA<<<(B_ * NCH_ * DI_) / 256, blk, 0, stream>>>(
            delta, u_bf, dbc, A_log + (size_t)i * DI_ * DS_, cs, csum);
        scan_passB<<<(B_ * DS_ * DI_) / 256, blk, 0, stream>>>(
            cs, csum, A_log + (size_t)i * DI_ * DS_);
        scan_passC<<<(B_ * NCH_ * DI_) / 256, blk, 0, stream>>>(
            delta, u_bf, dbc, A_log + (size_t)i * DI_ * DS_, cs, Dvp + (size_t)i * DI_, xz, y_bf);

        gemm_mfma<false, true, false><<<dim3(DM_ / 128, BL_ / 128), blk, 0, stream>>>(
            y_bf, outT, h, DM_, nullptr, DI_, DM_);
    }

    ln_rows<float><<<BL_, blk, 0, stream>>>(h, fn_g, fn_b, out);
}

// Round 3
// 945.995 us; speedup vs baseline: 2.8367x; 1.2698x over previous
//
#include <hip/hip_runtime.h>
#include <hip/hip_bf16.h>
#include <cstdint>
#include <cstddef>
#include <type_traits>

// ---------------- problem constants ----------------
constexpr int B_   = 2;
constexpr int L_   = 2048;
constexpr int F_   = 128;
constexpr int DM_  = 768;
constexpr int NL_  = 4;
constexpr int DS_  = 16;
constexpr int DC_  = 4;
constexpr int DI_  = 2 * DM_;          // 1536
constexpr int DR_  = (DM_ + 15) / 16;  // 48
constexpr int BL_  = B_ * L_;          // 4096 rows
constexpr int NXZ_ = 2 * DI_;          // 3072
constexpr int DBC_ = DR_ + 2 * DS_;    // 80
constexpr int NCH_ = 64;               // scan chunks (was 32; 768 blocks now)
constexpr int TCH_ = L_ / NCH_;        // 32 timesteps per chunk

#define DEV_INLINE __device__ __forceinline__

typedef __attribute__((ext_vector_type(8))) short  bf16x8;
typedef __attribute__((ext_vector_type(4))) float  f32x4;

DEV_INLINE float sigmoidf_(float x) { return 1.f / (1.f + __expf(-x)); }
DEV_INLINE float siluf_(float x)    { return x * sigmoidf_(x); }
DEV_INLINE float softplusf_(float x){ return x > 20.f ? x : log1pf(expf(x)); }

DEV_INLINE void gload_lds16(const void* g, void* l) {
    __builtin_amdgcn_global_load_lds(
        (const __attribute__((address_space(1))) void*)g,
        (__attribute__((address_space(3))) void*)l, 16, 0, 0);
}

// ---------------- bf16 MFMA GEMM (m97 structure) ----------------
// C[M,N] (+)= A[M,K] @ Bt[N,K]^T.  A,Bt bf16 row-major; C f32.
// 128x128 tile, BK=32, 256 threads = 4 waves, each wave one 64x64 quadrant.
// SPLITK>1: blockIdx.z picks a K-slice; epilogue atomicAdd (C must be zeroed).
template<bool BIAS, bool ACCUM, bool NMASK, int SPLITK = 1>
__global__ __launch_bounds__(256)
void gemm_mfma(const __hip_bfloat16* __restrict__ A,
               const __hip_bfloat16* __restrict__ Bt,
               float* __restrict__ C, int ldc,
               const float* __restrict__ bias,
               int K, int Nreal)
{
    __shared__ __hip_bfloat16 As[128 * 32];
    __shared__ __hip_bfloat16 Bs[128 * 32];

    const int tid  = threadIdx.x;
    const int lane = tid & 63;
    const int wv   = tid >> 6;
    const int wr   = wv >> 1;
    const int wc   = wv & 1;
    const int row0 = blockIdx.y * 128;
    const int col0 = blockIdx.x * 128;

    const int offb = tid * 16;
    const int srow = offb >> 6;          // 0..63
    const int skk  = (offb & 63) >> 1;   // 0,8,16,24
    const size_t ga0 = (size_t)(row0 + srow)      * K + skk;
    const size_t ga1 = (size_t)(row0 + 64 + srow) * K + skk;
    const size_t gb0 = (size_t)(col0 + srow)      * K + skk;
    const size_t gb1 = (size_t)(col0 + 64 + srow) * K + skk;

    const int fr = lane & 15, fq = lane >> 4;

    const int Kslice = K / SPLITK;
    const int kbeg = (SPLITK > 1) ? blockIdx.z * Kslice : 0;
    const int kend = kbeg + Kslice;

    f32x4 acc[4][4] = {};

    for (int k0 = kbeg; k0 < kend; k0 += 32) {
        gload_lds16(A  + ga0 + k0, &As[tid * 8]);
        gload_lds16(A  + ga1 + k0, &As[tid * 8 + 2048]);
        gload_lds16(Bt + gb0 + k0, &Bs[tid * 8]);
        gload_lds16(Bt + gb1 + k0, &Bs[tid * 8 + 2048]);
        __syncthreads();

        bf16x8 af[4], bfv[4];
        #pragma unroll
        for (int m = 0; m < 4; ++m)
            af[m] = *(const bf16x8*)&As[(wr * 64 + m * 16 + fr) * 32 + fq * 8];
        #pragma unroll
        for (int n = 0; n < 4; ++n)
            bfv[n] = *(const bf16x8*)&Bs[(wc * 64 + n * 16 + fr) * 32 + fq * 8];

        #pragma unroll
        for (int m = 0; m < 4; ++m)
            #pragma unroll
            for (int n = 0; n < 4; ++n)
                acc[m][n] = __builtin_amdgcn_mfma_f32_16x16x32_bf16(
                    af[m], bfv[n], acc[m][n], 0, 0, 0);
        __syncthreads();
    }

    #pragma unroll
    for (int m = 0; m < 4; ++m) {
        #pragma unroll
        for (int n = 0; n < 4; ++n) {
            const int col = col0 + wc * 64 + n * 16 + fr;
            if (NMASK && col >= Nreal) continue;
            #pragma unroll
            for (int r = 0; r < 4; ++r) {
                const int row = row0 + wr * 64 + m * 16 + fq * 4 + r;
                float v = acc[m][n][r];
                if (SPLITK > 1) {
                    atomicAdd(&C[(size_t)row * ldc + col], v);
                } else {
                    if (BIAS)  v += bias[col];
                    if (ACCUM) v += C[(size_t)row * ldc + col];
                    C[(size_t)row * ldc + col] = v;
                }
            }
        }
    }
}

__global__ __launch_bounds__(256)
void zero_f32(float* __restrict__ p, int n)
{
    const int i = blockIdx.x * 256 + threadIdx.x;
    if (i < n) p[i] = 0.f;
}

// ---------------- f32 [K][N] -> bf16 [Npad][K] transpose ----------------
__global__ __launch_bounds__(256)
void transpose_f32_bf16(const float* __restrict__ in, __hip_bfloat16* __restrict__ out,
                        int K, int N)
{
    __shared__ float t[32][33];
    const int n0 = blockIdx.x * 32, k0 = blockIdx.y * 32;
    const int tx = threadIdx.x, ty = threadIdx.y;
    #pragma unroll
    for (int r = 0; r < 4; ++r) {
        const int k = k0 + ty + r * 8;
        const int n = n0 + tx;
        t[ty + r * 8][tx] = (n < N) ? in[(size_t)k * N + n] : 0.f;
    }
    __syncthreads();
    #pragma unroll
    for (int r = 0; r < 4; ++r) {
        const int n = n0 + ty + r * 8;
        const int k = k0 + tx;
        out[(size_t)n * K + k] = __float2bfloat16(t[tx][ty + r * 8]);
    }
}

__global__ __launch_bounds__(256)
void cvt_bf16(const float* __restrict__ in, __hip_bfloat16* __restrict__ out, int n)
{
    const int i = blockIdx.x * 256 + threadIdx.x;
    if (i < n) out[i] = __float2bfloat16(in[i]);
}

// ---------------- generic tiled f32 GEMM (dt only) ----------------
template<bool BIAS, bool SOFTPLUS, bool ACCUM>
__global__ __launch_bounds__(256)
void gemm_f32(const float* __restrict__ A, int lda,
              const float* __restrict__ Bm, int ldb,
              float* __restrict__ C, int ldc,
              const float* __restrict__ bias,
              int M, int N, int K)
{
    __shared__ float As[16][64];
    __shared__ float Bs[16][64];

    const int tid  = threadIdx.x;
    const int col0 = blockIdx.x * 64;
    const int row0 = blockIdx.y * 64;
    const int ty   = tid >> 4;
    const int tx   = tid & 15;

    const int arow = row0 + (tid >> 2);
    const int akk  = (tid & 3) * 4;
    const int bkk  = tid >> 4;
    const int bcol = col0 + (tid & 15) * 4;

    float acc[4][4] = {};

    for (int k0 = 0; k0 < K; k0 += 16) {
        float4 av = *reinterpret_cast<const float4*>(&A[(size_t)arow * lda + k0 + akk]);
        float4 bv;
        if (bcol + 3 < N) {
            bv = *reinterpret_cast<const float4*>(&Bm[(size_t)(k0 + bkk) * ldb + bcol]);
        } else {
            float t0 = (bcol + 0 < N) ? Bm[(size_t)(k0 + bkk) * ldb + bcol + 0] : 0.f;
            float t1 = (bcol + 1 < N) ? Bm[(size_t)(k0 + bkk) * ldb + bcol + 1] : 0.f;
            float t2 = (bcol + 2 < N) ? Bm[(size_t)(k0 + bkk) * ldb + bcol + 2] : 0.f;
            float t3 = (bcol + 3 < N) ? Bm[(size_t)(k0 + bkk) * ldb + bcol + 3] : 0.f;
            bv = make_float4(t0, t1, t2, t3);
        }
        __syncthreads();
        {
            const int r = tid >> 2;
            As[akk + 0][r] = av.x;
            As[akk + 1][r] = av.y;
            As[akk + 2][r] = av.z;
            As[akk + 3][r] = av.w;
            *reinterpret_cast<float4*>(&Bs[bkk][(tid & 15) * 4]) = bv;
        }
        __syncthreads();

        #pragma unroll
        for (int k = 0; k < 16; ++k) {
            float4 a4 = *reinterpret_cast<const float4*>(&As[k][ty * 4]);
            float4 b4 = *reinterpret_cast<const float4*>(&Bs[k][tx * 4]);
            const float aa[4] = {a4.x, a4.y, a4.z, a4.w};
            const float bb[4] = {b4.x, b4.y, b4.z, b4.w};
            #pragma unroll
            for (int i = 0; i < 4; ++i)
                #pragma unroll
                for (int j = 0; j < 4; ++j)
                    acc[i][j] = fmaf(aa[i], bb[j], acc[i][j]);
        }
    }

    #pragma unroll
    for (int i = 0; i < 4; ++i) {
        const int r = row0 + ty * 4 + i;
        #pragma unroll
        for (int j = 0; j < 4; ++j) {
            const int c = col0 + tx * 4 + j;
            if (c < N) {
                float v = acc[i][j];
                if (BIAS)     v += bias[c];
                if (SOFTPLUS) v = softplusf_(v);
                if (ACCUM)    v += C[(size_t)r * ldc + c];
                C[(size_t)r * ldc + c] = v;
            }
        }
    }
}

// ---------------- row LayerNorm (768 = 3*256) ----------------
template<typename OT>
__global__ __launch_bounds__(256)
void ln_rows(const float* __restrict__ x, const float* __restrict__ g,
             const float* __restrict__ bb, OT* __restrict__ o)
{
    const int r = blockIdx.x;
    const float* xr = x + (size_t)r * DM_;
    const int tid = threadIdx.x;

    float v[3];
    float sum = 0.f, sumsq = 0.f;
    #pragma unroll
    for (int j = 0; j < 3; ++j) {
        v[j] = xr[tid + j * 256];
        sum   += v[j];
        sumsq += v[j] * v[j];
    }
    #pragma unroll
    for (int off = 32; off > 0; off >>= 1) {
        sum   += __shfl_xor(sum, off);
        sumsq += __shfl_xor(sumsq, off);
    }
    __shared__ float ws[2][4];
    const int lane = tid & 63, wid = tid >> 6;
    if (lane == 0) { ws[0][wid] = sum; ws[1][wid] = sumsq; }
    __syncthreads();
    const float ts  = ws[0][0] + ws[0][1] + ws[0][2] + ws[0][3];
    const float tsq = ws[1][0] + ws[1][1] + ws[1][2] + ws[1][3];
    const float m   = ts / DM_;
    const float var = tsq / DM_ - m * m;
    const float rs  = rsqrtf(var + 1e-5f);
    OT* orow = o + (size_t)r * DM_;
    #pragma unroll
    for (int j = 0; j < 3; ++j) {
        const int c = tid + j * 256;
        orow[c] = OT((v[j] - m) * rs * g[c] + bb[c]);
    }
}

// ---------------- depthwise causal conv (DC=4) + SiLU -> bf16 ----------------
__global__ __launch_bounds__(256)
void conv_silu(const float* __restrict__ xz, const float* __restrict__ cw,
               const float* __restrict__ cb, __hip_bfloat16* __restrict__ u)
{
    const int t0 = blockIdx.x * 256 + threadIdx.x;
    const int d = t0 % DI_;
    const int r = t0 / DI_;
    const int b = r / L_, l = r % L_;

    const float w0 = cw[d * DC_ + 0], w1 = cw[d * DC_ + 1];
    const float w2 = cw[d * DC_ + 2], w3 = cw[d * DC_ + 3];
    float acc = cb[d];
    const size_t base = (size_t)(b * L_) * NXZ_ + d;
    if (l - 3 >= 0) acc = fmaf(xz[base + (size_t)(l - 3) * NXZ_], w0, acc);
    if (l - 2 >= 0) acc = fmaf(xz[base + (size_t)(l - 2) * NXZ_], w1, acc);
    if (l - 1 >= 0) acc = fmaf(xz[base + (size_t)(l - 1) * NXZ_], w2, acc);
    acc = fmaf(xz[base + (size_t)l * NXZ_], w3, acc);
    u[(size_t)r * DI_ + d] = __float2bfloat16(siluf_(acc));
}

// ---------------- chunked selective scan ----------------
// pw[n] = exp(dv*Ar[n]).  PROG fast path: Ar[n] = Ar[0]*(n+1) (holds for the
// given A_init = arange(1..16)); build w^(n+1) by a log-depth product tree.
template<bool PROG>
DEV_INLINE void calc_pw(float dv, const float* Ar, float* pw)
{
    if (PROG) {
        pw[0] = __expf(dv * Ar[0]);
        #pragma unroll
        for (int n = 1; n < DS_; ++n) pw[n] = pw[(n - 1) >> 1] * pw[n >> 1];
    } else {
        #pragma unroll
        for (int n = 0; n < DS_; ++n) pw[n] = __expf(dv * Ar[n]);
    }
}

DEV_INLINE bool prog_check(const float* Ar)
{
    bool prog = true;
    #pragma unroll
    for (int n = 1; n < DS_; ++n)
        prog = prog && (fabsf(Ar[n] - Ar[0] * (n + 1)) <= 1e-4f * fabsf(Ar[n]) + 1e-30f);
    return prog;
}

// pass A: per (b, chunk, d): local scan from s=0 -> end state + sum(delta)
__global__ __launch_bounds__(256)
void scan_passA(const float* __restrict__ delta, const __hip_bfloat16* __restrict__ u,
                const float* __restrict__ dbc, const float* __restrict__ A_log,
                float* __restrict__ cs, float* __restrict__ csum)
{
    __shared__ float sB[TCH_][DS_];
    const int t0 = blockIdx.x * 256 + threadIdx.x;
    const int d = t0 % DI_;
    const int c = (t0 / DI_) % NCH_;
    const int b = t0 / (DI_ * NCH_);
    const int rowbase = b * L_ + c * TCH_;

    // stage B rows (shared by whole block: same (b,c) for all 256 threads)
    for (int i = threadIdx.x; i < TCH_ * DS_; i += 256) {
        const int t = i >> 4, n = i & 15;
        sB[t][n] = dbc[(size_t)(rowbase + t) * DBC_ + DR_ + n];
    }

    float Ar[DS_];
    #pragma unroll
    for (int n = 0; n < DS_; ++n) Ar[n] = -__expf(A_log[d * DS_ + n]);
    const bool prog = prog_check(Ar);

    __syncthreads();

    float s[DS_] = {};
    float sumd = 0.f;

    auto run = [&](auto PROGC) {
        constexpr bool PROG = decltype(PROGC)::value;
        for (int t = 0; t < TCH_; ++t) {
            const int row = rowbase + t;
            const float dv = delta[(size_t)row * DI_ + d];
            const float uv = __bfloat162float(u[(size_t)row * DI_ + d]);
            const float du = dv * uv;
            sumd += dv;
            float pw[DS_];
            calc_pw<PROG>(dv, Ar, pw);
            #pragma unroll
            for (int n = 0; n < DS_; ++n)
                s[n] = fmaf(s[n], pw[n], du * sB[t][n]);
        }
    };
    if (prog) run(std::true_type{}); else run(std::false_type{});

    const size_t cbase = ((size_t)(b * NCH_ + c) * DS_) * DI_ + d;
    #pragma unroll
    for (int n = 0; n < DS_; ++n) cs[cbase + (size_t)n * DI_] = s[n];
    csum[(size_t)(b * NCH_ + c) * DI_ + d] = sumd;
}

// pass B: sequential combine over chunks; cs becomes the chunk INITIAL state
__global__ __launch_bounds__(256)
void scan_passB(float* __restrict__ cs, const float* __restrict__ csum,
                const float* __restrict__ A_log)
{
    const int t0 = blockIdx.x * 256 + threadIdx.x;
    const int d = t0 % DI_;
    const int n = (t0 / DI_) % DS_;
    const int b = t0 / (DI_ * DS_);
    const float An = -__expf(A_log[d * DS_ + n]);

    float carry = 0.f;
    for (int c = 0; c < NCH_; ++c) {
        const size_t idx = ((size_t)(b * NCH_ + c) * DS_ + n) * DI_ + d;
        const float loc = cs[idx];
        cs[idx] = carry;
        carry = fmaf(carry, __expf(An * csum[(size_t)(b * NCH_ + c) * DI_ + d]), loc);
    }
}

// pass C: replay with correct initial state; fuse +u*Dv and *silu(z)
__global__ __launch_bounds__(256)
void scan_passC(const float* __restrict__ delta, const __hip_bfloat16* __restrict__ u,
                const float* __restrict__ dbc, const float* __restrict__ A_log,
                const float* __restrict__ cs, const float* __restrict__ Dvp,
                const float* __restrict__ xz, __hip_bfloat16* __restrict__ y)
{
    __shared__ float sBC[TCH_][2 * DS_];
    const int t0 = blockIdx.x * 256 + threadIdx.x;
    const int d = t0 % DI_;
    const int c = (t0 / DI_) % NCH_;
    const int b = t0 / (DI_ * NCH_);
    const int rowbase = b * L_ + c * TCH_;

    for (int i = threadIdx.x; i < TCH_ * 2 * DS_; i += 256) {
        const int t = i >> 5, j = i & 31;
        sBC[t][j] = dbc[(size_t)(rowbase + t) * DBC_ + DR_ + j];
    }

    float Ar[DS_];
    #pragma unroll
    for (int n = 0; n < DS_; ++n) Ar[n] = -__expf(A_log[d * DS_ + n]);
    const bool prog = prog_check(Ar);

    __syncthreads();

    float s[DS_];
    const size_t cbase = ((size_t)(b * NCH_ + c) * DS_) * DI_ + d;
    #pragma unroll
    for (int n = 0; n < DS_; ++n) s[n] = cs[cbase + (size_t)n * DI_];

    const float Dvd = Dvp[d];

    auto run = [&](auto PROGC) {
        constexpr bool PROG = decltype(PROGC)::value;
        for (int t = 0; t < TCH_; ++t) {
            const int row = rowbase + t;
            const float dv = delta[(size_t)row * DI_ + d];
            const float uv = __bfloat162float(u[(size_t)row * DI_ + d]);
            const float du = dv * uv;
            float pw[DS_];
            calc_pw<PROG>(dv, Ar, pw);
            float yv = 0.f;
            #pragma unroll
            for (int n = 0; n < DS_; ++n) {
                s[n] = fmaf(s[n], pw[n], du * sBC[t][n]);
                yv = fmaf(s[n], sBC[t][DS_ + n], yv);
            }
            yv = fmaf(uv, Dvd, yv);
            const float zv = xz[(size_t)row * NXZ_ + DI_ + d];
            yv *= siluf_(zv);
            y[(size_t)row * DI_ + d] = __float2bfloat16(yv);
        }
    };
    if (prog) run(std::true_type{}); else run(std::false_type{});
}

// ---------------- host launch ----------------
extern "C" void kernel_launch(void* const* d_in, const int* in_sizes, int n_in,
                              void* d_out, int out_size, void* d_ws, size_t ws_size,
                              hipStream_t stream)
{
    const float* x      = (const float*)d_in[0];
    const float* Wi     = (const float*)d_in[1];
    const float* bi     = (const float*)d_in[2];
    const float* ln_g   = (const float*)d_in[3];
    const float* ln_b   = (const float*)d_in[4];
    const float* in_w   = (const float*)d_in[5];
    const float* conv_w = (const float*)d_in[6];
    const float* conv_b = (const float*)d_in[7];
    const float* xproj  = (const float*)d_in[8];
    const float* dt_w   = (const float*)d_in[9];
    const float* dt_b   = (const float*)d_in[10];
    const float* A_log  = (const float*)d_in[11];
    const float* Dvp    = (const float*)d_in[12];
    const float* out_w  = (const float*)d_in[13];
    const float* fn_g   = (const float*)d_in[14];
    const float* fn_b   = (const float*)d_in[15];
    float* out = (float*)d_out;

    float* ws = (float*)d_ws;
    size_t off = 0;
    auto alloc = [&](size_t nfloats) { float* p = ws + off; off += nfloats; return p; };

    float* h     = alloc((size_t)BL_ * DM_);
    float* xz    = alloc((size_t)BL_ * NXZ_);
    float* dbc   = alloc((size_t)BL_ * DBC_);
    float* delta = alloc((size_t)BL_ * DI_);
    float* cs    = alloc((size_t)B_ * NCH_ * DS_ * DI_);
    float* csum  = alloc((size_t)B_ * NCH_ * DI_);
    __hip_bfloat16* hn_bf = (__hip_bfloat16*)alloc((size_t)BL_ * DM_ / 2);
    __hip_bfloat16* u_bf  = (__hip_bfloat16*)alloc((size_t)BL_ * DI_ / 2);
    __hip_bfloat16* y_bf  = (__hip_bfloat16*)alloc((size_t)BL_ * DI_ / 2);
    __hip_bfloat16* inT   = (__hip_bfloat16*)alloc((size_t)NXZ_ * DM_ / 2);
    __hip_bfloat16* outT  = (__hip_bfloat16*)alloc((size_t)DM_ * DI_ / 2);
    __hip_bfloat16* xprT  = (__hip_bfloat16*)alloc((size_t)128 * DI_ / 2);
    __hip_bfloat16* x_bf = y_bf;   // used only before layer 0
    __hip_bfloat16* WiT  = u_bf;   // used only before layer 0

    const dim3 blk(256);
    const dim3 tblk(32, 8);

    // input projection: h = x @ Wi + bi   (bf16 MFMA)
    cvt_bf16<<<(BL_ * F_ + 255) / 256, blk, 0, stream>>>(x, x_bf, BL_ * F_);
    transpose_f32_bf16<<<dim3(DM_ / 32, F_ / 32), tblk, 0, stream>>>(Wi, WiT, F_, DM_);
    gemm_mfma<true, false, false><<<dim3(DM_ / 128, BL_ / 128), blk, 0, stream>>>(
        x_bf, WiT, h, DM_, bi, F_, DM_);

    for (int i = 0; i < NL_; ++i) {
        transpose_f32_bf16<<<dim3(NXZ_ / 32, DM_ / 32), tblk, 0, stream>>>(
            in_w + (size_t)i * DM_ * NXZ_, inT, DM_, NXZ_);
        transpose_f32_bf16<<<dim3(DM_ / 32, DI_ / 32), tblk, 0, stream>>>(
            out_w + (size_t)i * DI_ * DM_, outT, DI_, DM_);
        transpose_f32_bf16<<<dim3(128 / 32, DI_ / 32), tblk, 0, stream>>>(
            xproj + (size_t)i * DI_ * DBC_, xprT, DI_, DBC_);

        ln_rows<__hip_bfloat16><<<BL_, blk, 0, stream>>>(
            h, ln_g + i * DM_, ln_b + i * DM_, hn_bf);

        gemm_mfma<false, false, false><<<dim3(NXZ_ / 128, BL_ / 128), blk, 0, stream>>>(
            hn_bf, inT, xz, NXZ_, nullptr, DM_, NXZ_);

        conv_silu<<<(BL_ * DI_) / 256, blk, 0, stream>>>(
            xz, conv_w + (size_t)i * DI_ * DC_, conv_b + (size_t)i * DI_, u_bf);

        // xproj GEMM: split-K x4 (grid was 32 blocks -> latency-bound)
        zero_f32<<<(BL_ * DBC_ + 255) / 256, blk, 0, stream>>>(dbc, BL_ * DBC_);
        gemm_mfma<false, false, true, 4><<<dim3(1, BL_ / 128, 4), blk, 0, stream>>>(
            u_bf, xprT, dbc, DBC_, nullptr, DI_, DBC_);

        gemm_f32<true, true, false><<<dim3(DI_ / 64, BL_ / 64), blk, 0, stream>>>(
            dbc, DBC_, dt_w + (size_t)i * DR_ * DI_, DI_, delta, DI_, dt_b + (size_t)i * DI_,
            BL_, DI_, DR_);

        scan_passA<<<(B_ * NCH_ * DI_) / 256, blk, 0, stream>>>(
            delta, u_bf, dbc, A_log + (size_t)i * DI_ * DS_, cs, csum);
        scan_passB<<<(B_ * DS_ * DI_) / 256, blk, 0, stream>>>(
            cs, csum, A_log + (size_t)i * DI_ * DS_);
        scan_passC<<<(B_ * NCH_ * DI_) / 256, blk, 0, stream>>>(
            delta, u_bf, dbc, A_log + (size_t)i * DI_ * DS_, cs, Dvp + (size_t)i * DI_, xz, y_bf);

        gemm_mfma<false, true, false><<<dim3(DM_ / 128, BL_ / 128), blk, 0, stream>>>(
            y_bf, outT, h, DM_, nullptr, DI_, DM_);
    }

    ln_rows<float><<<BL_, blk, 0, stream>>>(h, fn_g, fn_b, out);
}